// Round 5
// baseline (3419.763 us; speedup 1.0000x reference)
//
#include <hip/hip_runtime.h>
#include <hip/hip_bf16.h>
#include <stdint.h>

// Problem constants
#define T_STEPS 512
#define BATCH   64
#define IN_DIM  128
#define HID     1024
#define KTOT    (HID + IN_DIM)   // 1152: [H | X] vs [W_hh ; W_ih]
#define NWGS    64               // 4 groups x 16 producers
#define GP      16               // producers (WGs) per group
#define NCOLS   64               // h-cols per WG
#define NWAVES  4
#define THREADS (NWAVES * 64)

#define RING    16               // comm ring slots
#define DCLR    4                // clear-ahead depth (3 <= D <= 14 safe)
#define SLOT    (BATCH * HID)    // 65536 bf16 = 128 KB per slot
#define SENT    0x7F7F7F7F       // bf16 pair 0x7F7F = 3.39e38, unreachable by tanh
#define LDSB    (KTOT * NCOLS * 2)  // 147456 B dynamic LDS

typedef float f32x4 __attribute__((ext_vector_type(4)));
typedef int   i32x4 __attribute__((ext_vector_type(4)));
typedef short s16x8 __attribute__((ext_vector_type(8)));
typedef uint32_t u32x2 __attribute__((ext_vector_type(2)));

__device__ __forceinline__ uint32_t cvt_pk_bf16(float a, float b) {
    uint32_t r;
    asm("v_cvt_pk_bf16_f32 %0, %1, %2" : "=v"(r) : "v"(a), "v"(b));
    return r;   // low16 = bf16(a), high16 = bf16(b)
}

union frag_u { uint32_t u[4]; s16x8 s; };

__device__ __forceinline__ s16x8 pack_bf16x8(f32x4 a, f32x4 b) {
    frag_u f;
    f.u[0] = cvt_pk_bf16(a.x, a.y);
    f.u[1] = cvt_pk_bf16(a.z, a.w);
    f.u[2] = cvt_pk_bf16(b.x, b.y);
    f.u[3] = cvt_pk_bf16(b.z, b.w);
    return f.s;
}

__device__ __forceinline__ uint16_t f32_to_bf16(float v) {
    uint32_t u = __builtin_bit_cast(uint32_t, v);
    return (uint16_t)((u + 0x7FFFu + ((u >> 16) & 1u)) >> 16);
}

// fast tanh: 1 - 2/(e^{2x}+1); saturates correctly for |x| large
__device__ __forceinline__ float tanh_fast(float x) {
    float e = __expf(2.0f * x);
    return 1.0f - 2.0f * __builtin_amdgcn_rcpf(e + 1.0f);
}

__device__ __forceinline__ int imax(int a, int b) { return a > b ? a : b; }
__device__ __forceinline__ int max4(f32x4 v) {
    i32x4 a = __builtin_bit_cast(i32x4, v);
    return imax(imax(a.x, a.y), imax(a.z, a.w));
}

// 16 pipelined coherent (L1/L2-bypassing) 16B loads from one base pointer.
#define GLD16(D, P, TAIL)                                               \
    asm volatile(                                                       \
        "global_load_dwordx4 %0, %16, off sc0 sc1\n\t"                  \
        "global_load_dwordx4 %1, %16, off offset:64 sc0 sc1\n\t"        \
        "global_load_dwordx4 %2, %16, off offset:128 sc0 sc1\n\t"       \
        "global_load_dwordx4 %3, %16, off offset:192 sc0 sc1\n\t"       \
        "global_load_dwordx4 %4, %16, off offset:256 sc0 sc1\n\t"       \
        "global_load_dwordx4 %5, %16, off offset:320 sc0 sc1\n\t"       \
        "global_load_dwordx4 %6, %16, off offset:384 sc0 sc1\n\t"       \
        "global_load_dwordx4 %7, %16, off offset:448 sc0 sc1\n\t"       \
        "global_load_dwordx4 %8, %16, off offset:512 sc0 sc1\n\t"       \
        "global_load_dwordx4 %9, %16, off offset:576 sc0 sc1\n\t"       \
        "global_load_dwordx4 %10, %16, off offset:640 sc0 sc1\n\t"      \
        "global_load_dwordx4 %11, %16, off offset:704 sc0 sc1\n\t"      \
        "global_load_dwordx4 %12, %16, off offset:768 sc0 sc1\n\t"      \
        "global_load_dwordx4 %13, %16, off offset:832 sc0 sc1\n\t"      \
        "global_load_dwordx4 %14, %16, off offset:896 sc0 sc1\n\t"      \
        "global_load_dwordx4 %15, %16, off offset:960 sc0 sc1" TAIL     \
        : "=&v"(D[0]), "=&v"(D[1]), "=&v"(D[2]), "=&v"(D[3]),           \
          "=&v"(D[4]), "=&v"(D[5]), "=&v"(D[6]), "=&v"(D[7]),           \
          "=&v"(D[8]), "=&v"(D[9]), "=&v"(D[10]), "=&v"(D[11]),         \
          "=&v"(D[12]), "=&v"(D[13]), "=&v"(D[14]), "=&v"(D[15])        \
        : "v"(P)                                                        \
        : "memory")

__global__ void rnn_init_kernel(const float* __restrict__ H0,
                                uint16_t* __restrict__ comm) {
    // slot 0 of the ring holds bf16(H0), read by step t=0
    int i = blockIdx.x * 256 + threadIdx.x;
    for (int e = i; e < SLOT; e += 64 * 256)
        comm[e] = f32_to_bf16(H0[e]);
}

__global__ __launch_bounds__(THREADS, 1)
void rnn_seq_kernel(const float* __restrict__ X, const float* __restrict__ Wih,
                    const float* __restrict__ Whh, const float* __restrict__ bh,
                    float* __restrict__ out, uint16_t* __restrict__ comm)
{
    // W slice [KTOT x 64 cols] resident in dynamic LDS, bf16, MFMA-fragment
    // order: element (k, lc) at byte ((k>>5)*4 + (lc>>4))*1024 +
    // ((k>>3)&3)*256 + (lc&15)*16 + (k&7)*2.  Wave wv step-kk fragment =
    // base + wv*1024 + lane*16 + kk*4096: lane-linear, conflict-free,
    // bijective (round-3 lesson).
    extern __shared__ uint16_t Wlds[];

    const int tid = threadIdx.x;
    const int wg  = blockIdx.x;
    const int g   = wg >> 4;          // group 0..3 (16 batches each)
    const int p   = wg & 15;          // producer index within group (64 h-cols)
    const int bg0 = g * GP;           // first batch of my group
    const int hc0 = p * NCOLS;        // first h-col of my WG

    for (int e = tid; e < NCOLS * KTOT; e += THREADS) {
        int lc = e & 63;
        int k  = e >> 6;
        float w = (k < HID) ? Whh[(size_t)k * HID + hc0 + lc]
                            : Wih[(size_t)(k - HID) * HID + hc0 + lc];
        uint32_t off = (uint32_t)((((k >> 5) * 4 + (lc >> 4)) << 10)
                       + (((k >> 3) & 3) << 8) + ((lc & 15) << 4) + ((k & 7) << 1));
        *(uint16_t*)((char*)Wlds + off) = f32_to_bf16(w);
    }
    __syncthreads();

    const int lane = tid & 63;
    const int wv   = tid >> 6;
    const int cb   = lane & 15;       // batch-within-group AND B-frag col
    const int kg   = lane >> 4;       // k-group 0..3
    const int b    = bg0 + cb;        // global batch row this lane loads/owns
    const int h    = hc0 + wv * 16 + kg * 4;   // first of 4 h this lane owns
    const char* wfb = (const char*)Wlds + wv * 1024 + lane * 16;

    // D = mfma(Wfrag, Hfrag): row = h (kg*4+r), col = batch (cb).
    const f32x4 bv = *(const f32x4*)(bh + h);

    const uint16_t* rb = comm + (size_t)b * HID + kg * 8;   // consumer base
    uint16_t* wb = comm + (size_t)b * HID + h;              // producer base
    float* obase = out + (size_t)b * HID + h;

    u32x2 sent; sent.x = SENT; sent.y = SENT;

    for (int t = 0; t < T_STEPS; ++t) {
        f32x4 acc0 = {0.f, 0.f, 0.f, 0.f};
        f32x4 acc1 = {0.f, 0.f, 0.f, 0.f};

        // ---- Phase A: input projection (independent of recurrence) ----
        const float* xrow = X + ((size_t)t * BATCH + b) * IN_DIM;
        #pragma unroll
        for (int kk = 0; kk < IN_DIM / 32; ++kk) {
            int kidx = kk * 32 + kg * 8;
            f32x4 f0 = *(const f32x4*)(xrow + kidx);
            f32x4 f1 = *(const f32x4*)(xrow + kidx + 4);
            s16x8 xf = pack_bf16x8(f0, f1);
            s16x8 wf = *(const s16x8*)(wfb + (32 + kk) * 4096);
            if (kk & 1) acc1 = __builtin_amdgcn_mfma_f32_16x16x32_bf16(wf, xf, acc1, 0, 0, 0);
            else        acc0 = __builtin_amdgcn_mfma_f32_16x16x32_bf16(wf, xf, acc0, 0, 0, 0);
        }
        __builtin_amdgcn_sched_barrier(0);

        // ---- re-sentinel my 8B of slot (t+DCLR): drained by this step's
        //      vmcnt(16) tail (in-order retirement); peer spread <=1 step, so
        //      no one can be writing/reading that slot region now.
        {
            uint16_t* pc = wb + (size_t)((t + DCLR) & (RING - 1)) * SLOT;
            asm volatile("global_store_dwordx2 %0, %1, off sc0 sc1"
                         :: "v"(pc), "v"(sent) : "memory");
        }

        // ---- Phase B+C fused: poll the DATA of slot t until sentinel-free ----
        const uint16_t* pr = rb + (size_t)(t & (RING - 1)) * SLOT;
        f32x4 LA[16], LB[16];
        for (;;) {
            GLD16(LA, pr, "");                               // 16 in flight
            GLD16(LB, pr + 512, "\n\ts_waitcnt vmcnt(16)");  // drain thru LA
            __builtin_amdgcn_sched_barrier(0);               // LA regs now valid
            int m = (int)0x80000000;
            #pragma unroll
            for (int i = 0; i < 16; ++i) m = imax(m, max4(LA[i]));
            asm volatile("s_waitcnt vmcnt(0)" ::: "memory"); // LB regs valid
            __builtin_amdgcn_sched_barrier(0);
            #pragma unroll
            for (int i = 0; i < 16; ++i) m = imax(m, max4(LB[i]));
            if (__all(m != (int)SENT)) break;
        }

        // ---- recurrent GEMM: K=1024 over LA,LB (all regs resident) ----
        #pragma unroll
        for (int kk = 0; kk < 16; ++kk) {
            s16x8 wf = *(const s16x8*)(wfb + kk * 4096);
            s16x8 af = __builtin_bit_cast(s16x8, LA[kk]);
            if (kk & 1) acc1 = __builtin_amdgcn_mfma_f32_16x16x32_bf16(wf, af, acc1, 0, 0, 0);
            else        acc0 = __builtin_amdgcn_mfma_f32_16x16x32_bf16(wf, af, acc0, 0, 0, 0);
        }
        #pragma unroll
        for (int kk = 0; kk < 16; ++kk) {
            s16x8 wf = *(const s16x8*)(wfb + (16 + kk) * 4096);
            s16x8 af = __builtin_bit_cast(s16x8, LB[kk]);
            if (kk & 1) acc1 = __builtin_amdgcn_mfma_f32_16x16x32_bf16(wf, af, acc1, 0, 0, 0);
            else        acc0 = __builtin_amdgcn_mfma_f32_16x16x32_bf16(wf, af, acc0, 0, 0, 0);
        }

        // ---- Epilogue: bias+tanh; publish 8B comm (no ack, no flag) ----
        float th0 = tanh_fast(acc0[0] + acc1[0] + bv.x);
        float th1 = tanh_fast(acc0[1] + acc1[1] + bv.y);
        float th2 = tanh_fast(acc0[2] + acc1[2] + bv.z);
        float th3 = tanh_fast(acc0[3] + acc1[3] + bv.w);

        u32x2 cd;
        cd.x = cvt_pk_bf16(th0, th1);
        cd.y = cvt_pk_bf16(th2, th3);
        uint16_t* pw = wb + (size_t)((t + 1) & (RING - 1)) * SLOT;
        asm volatile("global_store_dwordx2 %0, %1, off sc0 sc1"
                     :: "v"(pw), "v"(cd) : "memory");

        // fp32 states (normal cached 16B store, off the critical path)
        f32x4 vo; vo.x = th0; vo.y = th1; vo.z = th2; vo.w = th3;
        *(f32x4*)(obase + (size_t)t * BATCH * HID) = vo;
        if (t == T_STEPS - 1)
            *(f32x4*)(obase + (size_t)T_STEPS * BATCH * HID) = vo;  // H_final
    }
}

extern "C" void kernel_launch(void* const* d_in, const int* in_sizes, int n_in,
                              void* d_out, int out_size, void* d_ws, size_t ws_size,
                              hipStream_t stream) {
    (void)in_sizes; (void)n_in; (void)out_size; (void)ws_size;
    const float* X   = (const float*)d_in[0];
    const float* Wih = (const float*)d_in[1];
    const float* Whh = (const float*)d_in[2];
    const float* bh  = (const float*)d_in[3];
    const float* H0  = (const float*)d_in[4];
    float* out = (float*)d_out;
    uint16_t* comm = (uint16_t*)d_ws;   // RING * SLOT bf16 = 2 MB

    hipFuncSetAttribute((const void*)rnn_seq_kernel,
                        hipFuncAttributeMaxDynamicSharedMemorySize, LDSB);

    // sentinel-fill the whole ring, then overwrite slot 0 with bf16(H0)
    hipMemsetAsync(comm, 0x7F, (size_t)RING * SLOT * 2, stream);
    hipLaunchKernelGGL(rnn_init_kernel, dim3(64), dim3(256), 0, stream, H0, comm);
    hipLaunchKernelGGL(rnn_seq_kernel, dim3(NWGS), dim3(THREADS), LDSB, stream,
                       X, Wih, Whh, bh, out, comm);
}

// Round 6
// 2941.786 us; speedup vs baseline: 1.1625x; 1.1625x over previous
//
#include <hip/hip_runtime.h>
#include <hip/hip_bf16.h>
#include <stdint.h>

// Problem constants
#define T_STEPS 512
#define BATCH   64
#define IN_DIM  128
#define HID     1024
#define KTOT    (HID + IN_DIM)   // 1152: [H | X] vs [W_hh ; W_ih]
#define NH      64               // one WG per 16-wide h-slice
#define NSLICE  16
#define NWAVES  4
#define THREADS (NWAVES * 64)

#define RING    16               // comm ring slots
#define DCLR    4                // clear-ahead depth (2 <= D <= 14 safe)
#define SLOT    (BATCH * HID)    // 65536 bf16 = 128 KB per slot
#define SENT    0x7F7F7F7F      // bf16 pair 0x7F7F = 3.39e38, unreachable by tanh

typedef float f32x4 __attribute__((ext_vector_type(4)));
typedef int   i32x4 __attribute__((ext_vector_type(4)));
typedef short s16x8 __attribute__((ext_vector_type(8)));
typedef uint32_t u32x2 __attribute__((ext_vector_type(2)));

__device__ __forceinline__ uint32_t cvt_pk_bf16(float a, float b) {
    uint32_t r;
    asm("v_cvt_pk_bf16_f32 %0, %1, %2" : "=v"(r) : "v"(a), "v"(b));
    return r;   // low16 = bf16(a), high16 = bf16(b)
}

union frag_u { uint32_t u[4]; s16x8 s; };

__device__ __forceinline__ s16x8 pack_bf16x8(f32x4 a, f32x4 b) {
    frag_u f;
    f.u[0] = cvt_pk_bf16(a.x, a.y);
    f.u[1] = cvt_pk_bf16(a.z, a.w);
    f.u[2] = cvt_pk_bf16(b.x, b.y);
    f.u[3] = cvt_pk_bf16(b.z, b.w);
    return f.s;
}

__device__ __forceinline__ uint16_t f32_to_bf16(float v) {
    uint32_t u = __builtin_bit_cast(uint32_t, v);
    return (uint16_t)((u + 0x7FFFu + ((u >> 16) & 1u)) >> 16);
}

// fast tanh: 1 - 2/(e^{2x}+1); saturates correctly for |x| large
__device__ __forceinline__ float tanh_fast(float x) {
    float e = __expf(2.0f * x);
    return 1.0f - 2.0f * __builtin_amdgcn_rcpf(e + 1.0f);
}

__device__ __forceinline__ int imax(int a, int b) { return a > b ? a : b; }
__device__ __forceinline__ int max4(f32x4 v) {
    i32x4 a = __builtin_bit_cast(i32x4, v);
    return imax(imax(a.x, a.y), imax(a.z, a.w));
}

// 16 pipelined coherent (L1/L2-bypassing) 16B loads from one base pointer.
#define GLD16(D, P, TAIL)                                               \
    asm volatile(                                                       \
        "global_load_dwordx4 %0, %16, off sc0 sc1\n\t"                  \
        "global_load_dwordx4 %1, %16, off offset:64 sc0 sc1\n\t"        \
        "global_load_dwordx4 %2, %16, off offset:128 sc0 sc1\n\t"       \
        "global_load_dwordx4 %3, %16, off offset:192 sc0 sc1\n\t"       \
        "global_load_dwordx4 %4, %16, off offset:256 sc0 sc1\n\t"       \
        "global_load_dwordx4 %5, %16, off offset:320 sc0 sc1\n\t"       \
        "global_load_dwordx4 %6, %16, off offset:384 sc0 sc1\n\t"       \
        "global_load_dwordx4 %7, %16, off offset:448 sc0 sc1\n\t"       \
        "global_load_dwordx4 %8, %16, off offset:512 sc0 sc1\n\t"       \
        "global_load_dwordx4 %9, %16, off offset:576 sc0 sc1\n\t"       \
        "global_load_dwordx4 %10, %16, off offset:640 sc0 sc1\n\t"      \
        "global_load_dwordx4 %11, %16, off offset:704 sc0 sc1\n\t"      \
        "global_load_dwordx4 %12, %16, off offset:768 sc0 sc1\n\t"      \
        "global_load_dwordx4 %13, %16, off offset:832 sc0 sc1\n\t"      \
        "global_load_dwordx4 %14, %16, off offset:896 sc0 sc1\n\t"      \
        "global_load_dwordx4 %15, %16, off offset:960 sc0 sc1" TAIL     \
        : "=&v"(D[0]), "=&v"(D[1]), "=&v"(D[2]), "=&v"(D[3]),           \
          "=&v"(D[4]), "=&v"(D[5]), "=&v"(D[6]), "=&v"(D[7]),           \
          "=&v"(D[8]), "=&v"(D[9]), "=&v"(D[10]), "=&v"(D[11]),         \
          "=&v"(D[12]), "=&v"(D[13]), "=&v"(D[14]), "=&v"(D[15])        \
        : "v"(P)                                                        \
        : "memory")

__global__ void rnn_init_kernel(const float* __restrict__ H0,
                                uint16_t* __restrict__ comm) {
    // slot 0 of the ring holds bf16(H0), read by step t=0
    int i = blockIdx.x * 256 + threadIdx.x;
    for (int e = i; e < SLOT; e += 64 * 256)
        comm[e] = f32_to_bf16(H0[e]);
}

__global__ __launch_bounds__(THREADS, 1)
void rnn_seq_kernel(const float* __restrict__ X, const float* __restrict__ Wih,
                    const float* __restrict__ Whh, const float* __restrict__ bh,
                    float* __restrict__ out, uint16_t* __restrict__ comm,
                    int* __restrict__ flags)
{
    // W slice resident in LDS in MFMA-fragment order (round-4 layout):
    // element (k, c) at byte (k>>5)*1024 + ((k>>3)&3)*256 + c*16 + (k&7)*2.
    // Wave fragment for step kk: base = lane*16 + offset kk*1024 ->
    // lane-linear, conflict-free, bijective.
    __shared__ uint16_t Wlds[NSLICE * KTOT];

    const int tid = threadIdx.x;
    const int wg  = blockIdx.x;
    const int h0  = wg * NSLICE;

    for (int e = tid; e < NSLICE * KTOT; e += THREADS) {
        int c = e & (NSLICE - 1);
        int k = e >> 4;
        float w = (k < HID) ? Whh[(size_t)k * HID + h0 + c]
                            : Wih[(size_t)(k - HID) * HID + h0 + c];
        uint32_t off = (uint32_t)((k >> 5) * 1024 + (((k >> 3) & 3) * 256)
                                  + c * 16 + (k & 7) * 2);
        *(uint16_t*)((char*)Wlds + off) = f32_to_bf16(w);
    }
    __syncthreads();

    const int lane = tid & 63;
    const int wv   = tid >> 6;
    const int cb   = lane & 15;         // batch-within-wave AND B-frag col
    const int kg   = lane >> 4;         // k-group 0..3
    const int b_ld = wv * 16 + cb;      // batch row this lane loads/owns
    const char* wfb = (const char*)Wlds + lane * 16;   // per-lane fragment base

    // D = mfma(Wfrag, Hfrag): rows = h (kg*4+r), cols = batch (cb).
    // Lane owns h = h0 + kg*4 + {0..3} for batch b_ld -> contiguous stores.
    const f32x4 bv = *(const f32x4*)(bh + h0 + kg * 4);

    int* fl = flags + wv * 64 + wg;             // my wave's flag
    const int* fpoll = flags + wv * 64 + lane;  // the 64 flags my wave needs

    const uint16_t* rb = comm + (size_t)b_ld * HID + kg * 8;     // consumer base
    uint16_t* wb = comm + (size_t)b_ld * HID + h0 + kg * 4;      // producer base
    float* obase = out + (size_t)b_ld * HID + h0 + kg * 4;

    u32x2 sentv; sentv.x = SENT; sentv.y = SENT;

    for (int t = 0; t < T_STEPS; ++t) {
        f32x4 acc0 = {0.f, 0.f, 0.f, 0.f};
        f32x4 acc1 = {0.f, 0.f, 0.f, 0.f};

        // ---- Phase A: input projection (independent of recurrence) ----
        const float* xrow = X + ((size_t)t * BATCH + b_ld) * IN_DIM;
        #pragma unroll
        for (int kk = 0; kk < IN_DIM / 32; ++kk) {
            int kidx = kk * 32 + kg * 8;
            f32x4 f0 = *(const f32x4*)(xrow + kidx);
            f32x4 f1 = *(const f32x4*)(xrow + kidx + 4);
            s16x8 xf = pack_bf16x8(f0, f1);
            s16x8 wf = *(const s16x8*)(wfb + (32 + kk) * 1024);
            if (kk & 1) acc1 = __builtin_amdgcn_mfma_f32_16x16x32_bf16(wf, xf, acc1, 0, 0, 0);
            else        acc0 = __builtin_amdgcn_mfma_f32_16x16x32_bf16(wf, xf, acc0, 0, 0, 0);
        }
        __builtin_amdgcn_sched_barrier(0);   // pin Phase A before the poll

        // ---- Phase B: cheap flag poll (detection only; NOT a data guarantee)
        if (t > 0) {
            for (;;) {
                int f;
                asm volatile("global_load_dword %0, %1, off sc0 sc1\n\t"
                             "s_waitcnt vmcnt(0)"
                             : "=v"(f) : "v"(fpoll) : "memory");
                if (__all(f >= t)) break;
            }
        }
        // clean vm queue so GLD16's vmcnt counts are exact (no-op after poll)
        asm volatile("s_waitcnt vmcnt(0)" ::: "memory");
        __builtin_amdgcn_sched_barrier(0);

        // ---- Phase C: load H[t] slot; sentinel-validate (flags may outrun
        //      data by one fabric-reorder window; retry is rare) ----
        const uint16_t* pr = rb + (size_t)(t & (RING - 1)) * SLOT;
        f32x4 LA[16], LB[16];
        for (;;) {
            GLD16(LA, pr, "");                               // 16 in flight
            GLD16(LB, pr + 512, "\n\ts_waitcnt vmcnt(16)");  // drain thru LA
            __builtin_amdgcn_sched_barrier(0);               // LA regs valid
            int m = (int)0x80000000;
            #pragma unroll
            for (int i = 0; i < 16; ++i) m = imax(m, max4(LA[i]));
            asm volatile("s_waitcnt vmcnt(0)" ::: "memory"); // LB regs valid
            __builtin_amdgcn_sched_barrier(0);
            #pragma unroll
            for (int i = 0; i < 16; ++i) m = imax(m, max4(LB[i]));
            if (__all(m != (int)SENT)) break;
        }

        // ---- recurrent GEMM: K=1024 over LA,LB (all regs resident) ----
        #pragma unroll
        for (int kk = 0; kk < 16; ++kk) {
            s16x8 wf = *(const s16x8*)(wfb + kk * 1024);
            s16x8 af = __builtin_bit_cast(s16x8, LA[kk]);
            if (kk & 1) acc1 = __builtin_amdgcn_mfma_f32_16x16x32_bf16(wf, af, acc1, 0, 0, 0);
            else        acc0 = __builtin_amdgcn_mfma_f32_16x16x32_bf16(wf, af, acc0, 0, 0, 0);
        }
        #pragma unroll
        for (int kk = 0; kk < 16; ++kk) {
            s16x8 wf = *(const s16x8*)(wfb + (16 + kk) * 1024);
            s16x8 af = __builtin_bit_cast(s16x8, LB[kk]);
            if (kk & 1) acc1 = __builtin_amdgcn_mfma_f32_16x16x32_bf16(wf, af, acc1, 0, 0, 0);
            else        acc0 = __builtin_amdgcn_mfma_f32_16x16x32_bf16(wf, af, acc0, 0, 0, 0);
        }

        // ---- Epilogue: bias+tanh; publish data then flag, NO drains ----
        float th0 = tanh_fast(acc0[0] + acc1[0] + bv.x);
        float th1 = tanh_fast(acc0[1] + acc1[1] + bv.y);
        float th2 = tanh_fast(acc0[2] + acc1[2] + bv.z);
        float th3 = tanh_fast(acc0[3] + acc1[3] + bv.w);

        u32x2 cd;
        cd.x = cvt_pk_bf16(th0, th1);
        cd.y = cvt_pk_bf16(th2, th3);
        uint16_t* pw = wb + (size_t)((t + 1) & (RING - 1)) * SLOT;
        asm volatile("global_store_dwordx2 %0, %1, off sc0 sc1"
                     :: "v"(pw), "v"(cd) : "memory");
        if (lane == 0) {
            int fv = t + 1;
            asm volatile("global_store_dword %0, %1, off sc0 sc1"
                         :: "v"(fl), "v"(fv) : "memory");
        }
        // re-sentinel my 8B of slot (t+1+DCLR): published at step t+DCLR,
        // read at t+1+DCLR -> DCLR-step gap vs any reorder; last stale read
        // of that slot index was ~RING steps ago (peer spread <=1 step).
        {
            uint16_t* pc = wb + (size_t)((t + 1 + DCLR) & (RING - 1)) * SLOT;
            asm volatile("global_store_dwordx2 %0, %1, off sc0 sc1"
                         :: "v"(pc), "v"(sentv) : "memory");
        }

        // fp32 states (normal cached 16B store, off the critical path)
        f32x4 vo; vo.x = th0; vo.y = th1; vo.z = th2; vo.w = th3;
        *(f32x4*)(obase + (size_t)t * BATCH * HID) = vo;
        if (t == T_STEPS - 1)
            *(f32x4*)(obase + (size_t)T_STEPS * BATCH * HID) = vo;  // H_final
    }
}

extern "C" void kernel_launch(void* const* d_in, const int* in_sizes, int n_in,
                              void* d_out, int out_size, void* d_ws, size_t ws_size,
                              hipStream_t stream) {
    (void)in_sizes; (void)n_in; (void)out_size; (void)ws_size;
    const float* X   = (const float*)d_in[0];
    const float* Wih = (const float*)d_in[1];
    const float* Whh = (const float*)d_in[2];
    const float* bh  = (const float*)d_in[3];
    const float* H0  = (const float*)d_in[4];
    float* out = (float*)d_out;

    uint16_t* comm = (uint16_t*)d_ws;                        // RING*SLOT bf16 = 2 MB
    int* flags = (int*)((char*)d_ws + (size_t)RING * SLOT * 2);  // 256 ints

    // sentinel-fill the ring, zero the flags, then bf16(H0) -> slot 0
    hipMemsetAsync(comm, 0x7F, (size_t)RING * SLOT * 2, stream);
    hipMemsetAsync(flags, 0, 256 * sizeof(int), stream);
    hipLaunchKernelGGL(rnn_init_kernel, dim3(64), dim3(256), 0, stream, H0, comm);
    hipLaunchKernelGGL(rnn_seq_kernel, dim3(NH), dim3(THREADS), 0, stream,
                       X, Wih, Whh, bh, out, comm, flags);
}

// Round 7
// 2888.858 us; speedup vs baseline: 1.1838x; 1.0183x over previous
//
#include <hip/hip_runtime.h>
#include <hip/hip_bf16.h>
#include <stdint.h>

// Problem constants
#define T_STEPS 512
#define BATCH   64
#define IN_DIM  128
#define HID     1024
#define KTOT    (HID + IN_DIM)   // 1152: [H | X] vs [W_hh ; W_ih]
#define NH      64               // one WG per 16-wide h-slice
#define NSLICE  16
#define NWAVES  4
#define THREADS (NWAVES * 64)

#define RING    16               // comm ring slots
#define DCLR    4                // clear-ahead depth (2 <= D <= 14 safe)
#define SLOT    (BATCH * HID)    // 65536 bf16 = 128 KB per slot
#define SENT    0x7F7F7F7F      // bf16 pair 0x7F7F = 3.39e38, unreachable by tanh
#define NFLAGS  (64 * NWAVES * 64)  // [consumer_wg][wv][producer_wg]

typedef float f32x4 __attribute__((ext_vector_type(4)));
typedef int   i32x4 __attribute__((ext_vector_type(4)));
typedef short s16x8 __attribute__((ext_vector_type(8)));
typedef uint32_t u32x2 __attribute__((ext_vector_type(2)));

__device__ __forceinline__ uint32_t cvt_pk_bf16(float a, float b) {
    uint32_t r;
    asm("v_cvt_pk_bf16_f32 %0, %1, %2" : "=v"(r) : "v"(a), "v"(b));
    return r;   // low16 = bf16(a), high16 = bf16(b)
}

union frag_u { uint32_t u[4]; s16x8 s; };

__device__ __forceinline__ s16x8 pack_bf16x8(f32x4 a, f32x4 b) {
    frag_u f;
    f.u[0] = cvt_pk_bf16(a.x, a.y);
    f.u[1] = cvt_pk_bf16(a.z, a.w);
    f.u[2] = cvt_pk_bf16(b.x, b.y);
    f.u[3] = cvt_pk_bf16(b.z, b.w);
    return f.s;
}

__device__ __forceinline__ uint16_t f32_to_bf16(float v) {
    uint32_t u = __builtin_bit_cast(uint32_t, v);
    return (uint16_t)((u + 0x7FFFu + ((u >> 16) & 1u)) >> 16);
}

// fast tanh: 1 - 2/(e^{2x}+1); saturates correctly for |x| large
__device__ __forceinline__ float tanh_fast(float x) {
    float e = __expf(2.0f * x);
    return 1.0f - 2.0f * __builtin_amdgcn_rcpf(e + 1.0f);
}

__device__ __forceinline__ int imax(int a, int b) { return a > b ? a : b; }
__device__ __forceinline__ int max4(f32x4 v) {
    i32x4 a = __builtin_bit_cast(i32x4, v);
    return imax(imax(a.x, a.y), imax(a.z, a.w));
}

// 16 pipelined coherent (L1/L2-bypassing) 16B loads from one base pointer.
#define GLD16(D, P, TAIL)                                               \
    asm volatile(                                                       \
        "global_load_dwordx4 %0, %16, off sc0 sc1\n\t"                  \
        "global_load_dwordx4 %1, %16, off offset:64 sc0 sc1\n\t"        \
        "global_load_dwordx4 %2, %16, off offset:128 sc0 sc1\n\t"       \
        "global_load_dwordx4 %3, %16, off offset:192 sc0 sc1\n\t"       \
        "global_load_dwordx4 %4, %16, off offset:256 sc0 sc1\n\t"       \
        "global_load_dwordx4 %5, %16, off offset:320 sc0 sc1\n\t"       \
        "global_load_dwordx4 %6, %16, off offset:384 sc0 sc1\n\t"       \
        "global_load_dwordx4 %7, %16, off offset:448 sc0 sc1\n\t"       \
        "global_load_dwordx4 %8, %16, off offset:512 sc0 sc1\n\t"       \
        "global_load_dwordx4 %9, %16, off offset:576 sc0 sc1\n\t"       \
        "global_load_dwordx4 %10, %16, off offset:640 sc0 sc1\n\t"      \
        "global_load_dwordx4 %11, %16, off offset:704 sc0 sc1\n\t"      \
        "global_load_dwordx4 %12, %16, off offset:768 sc0 sc1\n\t"      \
        "global_load_dwordx4 %13, %16, off offset:832 sc0 sc1\n\t"      \
        "global_load_dwordx4 %14, %16, off offset:896 sc0 sc1\n\t"      \
        "global_load_dwordx4 %15, %16, off offset:960 sc0 sc1" TAIL     \
        : "=&v"(D[0]), "=&v"(D[1]), "=&v"(D[2]), "=&v"(D[3]),           \
          "=&v"(D[4]), "=&v"(D[5]), "=&v"(D[6]), "=&v"(D[7]),           \
          "=&v"(D[8]), "=&v"(D[9]), "=&v"(D[10]), "=&v"(D[11]),         \
          "=&v"(D[12]), "=&v"(D[13]), "=&v"(D[14]), "=&v"(D[15])        \
        : "v"(P)                                                        \
        : "memory")

__global__ void rnn_init_kernel(const float* __restrict__ H0,
                                uint16_t* __restrict__ comm) {
    // slot 0 of the ring holds bf16(H0), read by step t=0
    int i = blockIdx.x * 256 + threadIdx.x;
    for (int e = i; e < SLOT; e += 64 * 256)
        comm[e] = f32_to_bf16(H0[e]);
}

__global__ __launch_bounds__(THREADS, 1)
void rnn_seq_kernel(const float* __restrict__ X, const float* __restrict__ Wih,
                    const float* __restrict__ Whh, const float* __restrict__ bh,
                    float* __restrict__ out, uint16_t* __restrict__ comm,
                    int* __restrict__ flags2)
{
    // W slice resident in LDS in MFMA-fragment order (round-4 layout):
    // element (k, c) at byte (k>>5)*1024 + ((k>>3)&3)*256 + c*16 + (k&7)*2.
    // Wave fragment for step kk: base = lane*16 + offset kk*1024 ->
    // lane-linear, conflict-free, bijective.
    __shared__ uint16_t Wlds[NSLICE * KTOT];

    const int tid = threadIdx.x;
    const int wg  = blockIdx.x;
    const int h0  = wg * NSLICE;

    for (int e = tid; e < NSLICE * KTOT; e += THREADS) {
        int c = e & (NSLICE - 1);
        int k = e >> 4;
        float w = (k < HID) ? Whh[(size_t)k * HID + h0 + c]
                            : Wih[(size_t)(k - HID) * HID + h0 + c];
        uint32_t off = (uint32_t)((k >> 5) * 1024 + (((k >> 3) & 3) * 256)
                                  + c * 16 + (k & 7) * 2);
        *(uint16_t*)((char*)Wlds + off) = f32_to_bf16(w);
    }
    __syncthreads();

    const int lane = tid & 63;
    const int wv   = tid >> 6;
    const int cb   = lane & 15;         // batch-within-wave AND B-frag col
    const int kg   = lane >> 4;         // k-group 0..3
    const int b_ld = wv * 16 + cb;      // batch row this lane loads/owns
    const char* wfb = (const char*)Wlds + lane * 16;   // per-lane fragment base

    // D = mfma(Wfrag, Hfrag): rows = h (kg*4+r), cols = batch (cb).
    // Lane owns h = h0 + kg*4 + {0..3} for batch b_ld -> contiguous stores.
    const f32x4 bv = *(const f32x4*)(bh + h0 + kg * 4);

    // TRANSPOSED flag matrix: flags2[consumer_wg][wv][producer_wg].
    // Consumer wave (wg,wv) polls 64 ints PRIVATE to it (4 lines, 1 reader).
    // Producer wave (wg,wv) scatter-stores t+1 into all 64 consumer blocks.
    const int* fpoll = flags2 + (wg * NWAVES + wv) * 64 + lane;
    int* fst = flags2 + (lane * NWAVES + wv) * 64 + wg;

    const uint16_t* rb = comm + (size_t)b_ld * HID + kg * 8;     // consumer base
    uint16_t* wb = comm + (size_t)b_ld * HID + h0 + kg * 4;      // producer base
    float* obase = out + (size_t)b_ld * HID + h0 + kg * 4;

    u32x2 sentv; sentv.x = SENT; sentv.y = SENT;

    for (int t = 0; t < T_STEPS; ++t) {
        f32x4 acc0 = {0.f, 0.f, 0.f, 0.f};
        f32x4 acc1 = {0.f, 0.f, 0.f, 0.f};

        // ---- Phase A: input projection (independent of recurrence) ----
        const float* xrow = X + ((size_t)t * BATCH + b_ld) * IN_DIM;
        #pragma unroll
        for (int kk = 0; kk < IN_DIM / 32; ++kk) {
            int kidx = kk * 32 + kg * 8;
            f32x4 f0 = *(const f32x4*)(xrow + kidx);
            f32x4 f1 = *(const f32x4*)(xrow + kidx + 4);
            s16x8 xf = pack_bf16x8(f0, f1);
            s16x8 wf = *(const s16x8*)(wfb + (32 + kk) * 1024);
            if (kk & 1) acc1 = __builtin_amdgcn_mfma_f32_16x16x32_bf16(wf, xf, acc1, 0, 0, 0);
            else        acc0 = __builtin_amdgcn_mfma_f32_16x16x32_bf16(wf, xf, acc0, 0, 0, 0);
        }
        __builtin_amdgcn_sched_barrier(0);   // pin Phase A before the poll

        // ---- Phase B: private-line flag poll (detection only) ----
        if (t > 0) {
            for (;;) {
                int f;
                asm volatile("global_load_dword %0, %1, off sc0 sc1\n\t"
                             "s_waitcnt vmcnt(0)"
                             : "=v"(f) : "v"(fpoll) : "memory");
                if (__all(f >= t)) break;
            }
        }
        // drain vm queue (incl. prior-step stores!) so GLD16's vmcnt counts
        // are exact -- do not remove.
        asm volatile("s_waitcnt vmcnt(0)" ::: "memory");
        __builtin_amdgcn_sched_barrier(0);

        // ---- Phase C: load H[t] slot; sentinel-validate (flags may outrun
        //      data by one fabric-reorder window; retry is rare) ----
        const uint16_t* pr = rb + (size_t)(t & (RING - 1)) * SLOT;
        f32x4 LA[16], LB[16];
        for (;;) {
            GLD16(LA, pr, "");                               // 16 in flight
            GLD16(LB, pr + 512, "\n\ts_waitcnt vmcnt(16)");  // drain thru LA
            __builtin_amdgcn_sched_barrier(0);               // LA regs valid
            int m = (int)0x80000000;
            #pragma unroll
            for (int i = 0; i < 16; ++i) m = imax(m, max4(LA[i]));
            asm volatile("s_waitcnt vmcnt(0)" ::: "memory"); // LB regs valid
            __builtin_amdgcn_sched_barrier(0);
            #pragma unroll
            for (int i = 0; i < 16; ++i) m = imax(m, max4(LB[i]));
            if (__all(m != (int)SENT)) break;
        }

        // ---- recurrent GEMM: K=1024 over LA,LB (all regs resident) ----
        #pragma unroll
        for (int kk = 0; kk < 16; ++kk) {
            s16x8 wf = *(const s16x8*)(wfb + kk * 1024);
            s16x8 af = __builtin_bit_cast(s16x8, LA[kk]);
            if (kk & 1) acc1 = __builtin_amdgcn_mfma_f32_16x16x32_bf16(wf, af, acc1, 0, 0, 0);
            else        acc0 = __builtin_amdgcn_mfma_f32_16x16x32_bf16(wf, af, acc0, 0, 0, 0);
        }
        #pragma unroll
        for (int kk = 0; kk < 16; ++kk) {
            s16x8 wf = *(const s16x8*)(wfb + (16 + kk) * 1024);
            s16x8 af = __builtin_bit_cast(s16x8, LB[kk]);
            if (kk & 1) acc1 = __builtin_amdgcn_mfma_f32_16x16x32_bf16(wf, af, acc1, 0, 0, 0);
            else        acc0 = __builtin_amdgcn_mfma_f32_16x16x32_bf16(wf, af, acc0, 0, 0, 0);
        }

        // ---- Epilogue: bias+tanh; publish data then flags, NO drains ----
        float th0 = tanh_fast(acc0[0] + acc1[0] + bv.x);
        float th1 = tanh_fast(acc0[1] + acc1[1] + bv.y);
        float th2 = tanh_fast(acc0[2] + acc1[2] + bv.z);
        float th3 = tanh_fast(acc0[3] + acc1[3] + bv.w);

        u32x2 cd;
        cd.x = cvt_pk_bf16(th0, th1);
        cd.y = cvt_pk_bf16(th2, th3);
        uint16_t* pw = wb + (size_t)((t + 1) & (RING - 1)) * SLOT;
        asm volatile("global_store_dwordx2 %0, %1, off sc0 sc1"
                     :: "v"(pw), "v"(cd) : "memory");
        {   // scatter flag t+1 into every consumer's private block
            int fv = t + 1;
            asm volatile("global_store_dword %0, %1, off sc0 sc1"
                         :: "v"(fst), "v"(fv) : "memory");
        }
        // re-sentinel my 8B of slot (t+1+DCLR): published at step t+DCLR,
        // read at t+1+DCLR -> DCLR-step gap vs any reorder; last stale read
        // of that slot index was ~RING steps ago (peer spread <=1 step).
        {
            uint16_t* pc = wb + (size_t)((t + 1 + DCLR) & (RING - 1)) * SLOT;
            asm volatile("global_store_dwordx2 %0, %1, off sc0 sc1"
                         :: "v"(pc), "v"(sentv) : "memory");
        }

        // fp32 states (normal cached 16B store, off the critical path)
        f32x4 vo; vo.x = th0; vo.y = th1; vo.z = th2; vo.w = th3;
        *(f32x4*)(obase + (size_t)t * BATCH * HID) = vo;
        if (t == T_STEPS - 1)
            *(f32x4*)(obase + (size_t)T_STEPS * BATCH * HID) = vo;  // H_final
    }
}

extern "C" void kernel_launch(void* const* d_in, const int* in_sizes, int n_in,
                              void* d_out, int out_size, void* d_ws, size_t ws_size,
                              hipStream_t stream) {
    (void)in_sizes; (void)n_in; (void)out_size; (void)ws_size;
    const float* X   = (const float*)d_in[0];
    const float* Wih = (const float*)d_in[1];
    const float* Whh = (const float*)d_in[2];
    const float* bh  = (const float*)d_in[3];
    const float* H0  = (const float*)d_in[4];
    float* out = (float*)d_out;

    uint16_t* comm = (uint16_t*)d_ws;                        // RING*SLOT bf16 = 2 MB
    int* flags2 = (int*)((char*)d_ws + (size_t)RING * SLOT * 2);  // 16K ints = 64 KB

    // sentinel-fill the ring, zero the flags, then bf16(H0) -> slot 0
    hipMemsetAsync(comm, 0x7F, (size_t)RING * SLOT * 2, stream);
    hipMemsetAsync(flags2, 0, NFLAGS * sizeof(int), stream);
    hipLaunchKernelGGL(rnn_init_kernel, dim3(64), dim3(256), 0, stream, H0, comm);
    hipLaunchKernelGGL(rnn_seq_kernel, dim3(NH), dim3(THREADS), 0, stream,
                       X, Wih, Whh, bh, out, comm, flags2);
}

// Round 10
// 2057.931 us; speedup vs baseline: 1.6617x; 1.4038x over previous
//
#include <hip/hip_runtime.h>
#include <hip/hip_bf16.h>
#include <stdint.h>

// Problem constants
#define T_STEPS 512
#define BATCH   64
#define IN_DIM  128
#define HID     1024
#define KTOT    (HID + IN_DIM)   // 1152: [H | X] vs [W_hh ; W_ih]
#define NWAVES  4
#define THREADS (NWAVES * 64)

// 2 batch-groups x 32 col-slices; each WG: 32 batches x 32 h-cols.
// H-tile for the group is staged in LDS once per WG per step and shared by
// the 4 waves -> coherent comm volume 8MB -> 4MB/step.
#define NGRP    2
#define GB      32               // batches per group
#define NSL     32               // col-slice WGs per group
#define NCOLS   32               // h-cols per WG (2 MFMA col-tiles)
#define NKK     36               // K-steps of 32 (1152/32)
#define WBYTES  (KTOT * NCOLS * 2)    // 73728
#define HBYTES  (GB * HID * 2)        // 65536
#define LDSB    (WBYTES + HBYTES)     // 139264 -> 1 WG/CU

#define RING    16               // comm ring slots (2 MB)
#define DCLR    4                // clear-ahead depth
#define SLOT    (BATCH * HID)    // 65536 bf16 = 128 KB per slot
#define SENT    0x7F7F7F7F       // bf16 pair 3.39e38, unreachable by tanh
#define NFLAGS  (NGRP * NSL * NWAVES * NSL)   // 8192 ints

typedef float f32x4 __attribute__((ext_vector_type(4)));
typedef int   i32x4 __attribute__((ext_vector_type(4)));
typedef short s16x8 __attribute__((ext_vector_type(8)));
typedef uint32_t u32x2 __attribute__((ext_vector_type(2)));

#define MFMA16 __builtin_amdgcn_mfma_f32_16x16x32_bf16

__device__ __forceinline__ uint32_t cvt_pk_bf16(float a, float b) {
    uint32_t r;
    asm("v_cvt_pk_bf16_f32 %0, %1, %2" : "=v"(r) : "v"(a), "v"(b));
    return r;   // low16 = bf16(a), high16 = bf16(b)
}

union frag_u { uint32_t u[4]; s16x8 s; };

__device__ __forceinline__ s16x8 pack_bf16x8(f32x4 a, f32x4 b) {
    frag_u f;
    f.u[0] = cvt_pk_bf16(a.x, a.y);
    f.u[1] = cvt_pk_bf16(a.z, a.w);
    f.u[2] = cvt_pk_bf16(b.x, b.y);
    f.u[3] = cvt_pk_bf16(b.z, b.w);
    return f.s;
}

__device__ __forceinline__ uint16_t f32_to_bf16(float v) {
    uint32_t u = __builtin_bit_cast(uint32_t, v);
    return (uint16_t)((u + 0x7FFFu + ((u >> 16) & 1u)) >> 16);
}

// fast tanh: 1 - 2/(e^{2x}+1); saturates correctly for |x| large
__device__ __forceinline__ float tanh_fast(float x) {
    float e = __expf(2.0f * x);
    return 1.0f - 2.0f * __builtin_amdgcn_rcpf(e + 1.0f);
}

__device__ __forceinline__ int imax(int a, int b) { return a > b ? a : b; }
__device__ __forceinline__ int max4(f32x4 v) {
    i32x4 a = __builtin_bit_cast(i32x4, v);
    return imax(imax(a.x, a.y), imax(a.z, a.w));
}

__global__ void rnn_init_kernel(const float* __restrict__ H0,
                                uint16_t* __restrict__ comm) {
    // slot 0 of the ring holds bf16(H0), read by step t=0
    int i = blockIdx.x * 256 + threadIdx.x;
    for (int e = i; e < SLOT; e += 64 * 256)
        comm[e] = f32_to_bf16(H0[e]);
}

__global__ __launch_bounds__(THREADS, 1)
void rnn_seq_kernel(const float* __restrict__ X, const float* __restrict__ Wih,
                    const float* __restrict__ Whh, const float* __restrict__ bh,
                    float* __restrict__ out, uint16_t* __restrict__ comm,
                    int* __restrict__ flags2)
{
    extern __shared__ char lds[];        // [0,73728): W frags; [73728,..): H tile
    char* Hl = lds + WBYTES;

    const int tid = threadIdx.x;
    const int wg  = blockIdx.x;          // g*NSL + p
    const int g   = wg >> 5;
    const int p   = wg & 31;
    const int hc0 = p * NCOLS;
    const int bg0 = g * GB;

    // ---- stage W cols [hc0,hc0+32) into LDS, MFMA-fragment order:
    // tile n=c2>>4 (2 tiles), element (k,c): byte ((n*NKK + k>>5)<<10)
    // + ((k>>3)&3)<<8 + c<<4 + (k&7)<<1. Lane-linear reads, bijective.
    for (int e = tid; e < NCOLS * KTOT; e += THREADS) {
        int c2 = e & 31;
        int k  = e >> 5;
        int n  = c2 >> 4, c = c2 & 15;
        float w = (k < HID) ? Whh[(size_t)k * HID + hc0 + c2]
                            : Wih[(size_t)(k - HID) * HID + hc0 + c2];
        uint32_t off = ((uint32_t)(n * NKK + (k >> 5)) << 10)
                     + (((k >> 3) & 3) << 8) + (c << 4) + ((k & 7) << 1);
        *(uint16_t*)(lds + off) = f32_to_bf16(w);
    }
    __syncthreads();

    const int lane = tid & 63, wv = tid >> 6;
    const int cb = lane & 15, kg = lane >> 4;
    const int bt = wv >> 1, ct = wv & 1;       // wave's (batch-tile, col-tile)
    const int b  = bg0 + bt * 16 + cb;         // global batch row
    const int h  = hc0 + ct * 16 + kg * 4;     // first of 4 h-cols this lane owns
    const char* wfb = lds + (size_t)ct * NKK * 1024 + lane * 16;
    const f32x4 bv = *(const f32x4*)(bh + h);

    // per-WG flags: cell [consumer_wg][consumer_wv][producer p'].
    // Producer flags AFTER the epilogue __syncthreads (drains all publishes),
    // wave wv covers consumer-wave row wv.
    const int* fpoll = flags2 + (wg * NWAVES + wv) * NSL + (lane & 31);
    int* fst = flags2 + ((g * NSL + (lane & 31)) * NWAVES + wv) * NSL + p;

    uint16_t* wb = comm + (size_t)b * HID + h;   // publish/clear base
    float* ob = out + (size_t)b * HID + h;

    // A-frag LDS read: row-major H tile + XOR swizzle ^((row&7)<<4)
    const int r = bt * 16 + cb;                  // row within group tile
    const uint32_t abase = (uint32_t)r * 2048 + (uint32_t)kg * 16;
    const uint32_t aswz  = (uint32_t)(r & 7) << 4;

    const size_t gstage = (size_t)bg0 * HID;     // group rows base (elems)
    u32x2 sentv; sentv.x = SENT; sentv.y = SENT;

    for (int t = 0; t < T_STEPS; ++t) {
        f32x4 acc0 = {0.f,0.f,0.f,0.f}, acc1 = {0.f,0.f,0.f,0.f};

        // ---- Phase A: X projection (independent; overlaps producer wait) ----
        const float* xrow = X + ((size_t)t * BATCH + b) * IN_DIM;
        #pragma unroll
        for (int kk = 0; kk < 4; ++kk) {
            int kidx = kk * 32 + kg * 8;
            f32x4 f0 = *(const f32x4*)(xrow + kidx);
            f32x4 f1 = *(const f32x4*)(xrow + kidx + 4);
            s16x8 xf = pack_bf16x8(f0, f1);
            s16x8 wf = *(const s16x8*)(wfb + (32 + kk) * 1024);
            if (kk & 1) acc1 = MFMA16(wf, xf, acc1, 0, 0, 0);
            else        acc0 = MFMA16(wf, xf, acc0, 0, 0, 0);
        }
        __builtin_amdgcn_sched_barrier(0);

        // ---- Phase B: private-line flag poll (1 line per WG-wave) ----
        if (t > 0) {
            for (;;) {
                int f;
                asm volatile("global_load_dword %0, %1, off sc0 sc1\n\t"
                             "s_waitcnt vmcnt(0)"
                             : "=v"(f) : "v"(fpoll) : "memory");
                if (__all(f >= t)) break;
            }
        }
        asm volatile("s_waitcnt vmcnt(0)" ::: "memory");
        __builtin_amdgcn_sched_barrier(0);

        // ---- Phase C: cooperatively stage group's H rows (64 KB) into LDS.
        // Thread covers 16 interleaved 16B blocks j=i*256+tid (lane-linear).
        // Sentinel-validate in regs (retry rare: flags gate, data precedes).
        const char* gb = (const char*)(comm + (size_t)(t & (RING - 1)) * SLOT
                                       + gstage) + tid * 16;
        f32x4 L[16];
        for (;;) {
            #pragma unroll
            for (int i = 0; i < 16; ++i)
                asm volatile("global_load_dwordx4 %0, %1, off sc0 sc1"
                             : "=v"(L[i]) : "v"(gb + (size_t)i * 4096) : "memory");
            asm volatile("s_waitcnt vmcnt(0)" ::: "memory");
            __builtin_amdgcn_sched_barrier(0);
            int m = (int)0x80000000;
            #pragma unroll
            for (int i = 0; i < 16; ++i) m = imax(m, max4(L[i]));
            if (__all(m != (int)SENT)) break;
        }
        #pragma unroll
        for (int i = 0; i < 16; ++i) {
            int j = i * 256 + tid;
            uint32_t off = ((uint32_t)j * 16) ^ ((((uint32_t)j >> 7) & 7) << 4);
            *(f32x4*)(Hl + off) = L[i];
        }
        __syncthreads();                 // barrier 1: H tile ready

        // ---- recurrent GEMM: K=1024, A-frags from shared LDS H tile ----
        #pragma unroll
        for (int kk = 0; kk < 32; ++kk) {
            s16x8 af = *(const s16x8*)(Hl + ((abase + (uint32_t)kk * 64) ^ aswz));
            s16x8 wf = *(const s16x8*)(wfb + kk * 1024);
            if (kk & 1) acc1 = MFMA16(wf, af, acc1, 0, 0, 0);
            else        acc0 = MFMA16(wf, af, acc0, 0, 0, 0);
        }

        // ---- Epilogue: bias+tanh; publish 8B; barrier; flag; clear; out ----
        float t0 = tanh_fast(acc0[0] + acc1[0] + bv.x);
        float t1 = tanh_fast(acc0[1] + acc1[1] + bv.y);
        float t2 = tanh_fast(acc0[2] + acc1[2] + bv.z);
        float t3 = tanh_fast(acc0[3] + acc1[3] + bv.w);

        u32x2 cd;
        cd.x = cvt_pk_bf16(t0, t1);
        cd.y = cvt_pk_bf16(t2, t3);
        uint16_t* pw = wb + (size_t)((t + 1) & (RING - 1)) * SLOT;
        asm volatile("global_store_dwordx2 %0, %1, off sc0 sc1"
                     :: "v"(pw), "v"(cd) : "memory");
        // barrier 2: implicit vmcnt(0) drains ALL waves' publishes; also
        // guarantees H-tile LDS reads done before next step's staging writes.
        __syncthreads();
        if (lane < 32) {
            int fv = t + 1;
            asm volatile("global_store_dword %0, %1, off sc0 sc1"
                         :: "v"(fst), "v"(fv) : "memory");
        }
        {   // re-sentinel own cells of slot (t+1+DCLR): 4-step guard; this
            // store is drained by next iteration's vmcnt(0) before any use.
            uint16_t* pc = wb + (size_t)((t + 1 + DCLR) & (RING - 1)) * SLOT;
            asm volatile("global_store_dwordx2 %0, %1, off sc0 sc1"
                         :: "v"(pc), "v"(sentv) : "memory");
        }

        // fp32 states (normal cached 16B store, off the critical path)
        f32x4 vo; vo.x = t0; vo.y = t1; vo.z = t2; vo.w = t3;
        *(f32x4*)(ob + (size_t)t * BATCH * HID) = vo;
        if (t == T_STEPS - 1)
            *(f32x4*)(ob + (size_t)T_STEPS * BATCH * HID) = vo;  // H_final
    }
}

extern "C" void kernel_launch(void* const* d_in, const int* in_sizes, int n_in,
                              void* d_out, int out_size, void* d_ws, size_t ws_size,
                              hipStream_t stream) {
    (void)in_sizes; (void)n_in; (void)out_size; (void)ws_size;
    const float* X   = (const float*)d_in[0];
    const float* Wih = (const float*)d_in[1];
    const float* Whh = (const float*)d_in[2];
    const float* bh  = (const float*)d_in[3];
    const float* H0  = (const float*)d_in[4];
    float* out = (float*)d_out;

    uint16_t* comm = (uint16_t*)d_ws;                             // 2 MB ring
    int* flags2 = (int*)((char*)d_ws + (size_t)RING * SLOT * 2);  // 8192 ints

    hipFuncSetAttribute((const void*)rnn_seq_kernel,
                        hipFuncAttributeMaxDynamicSharedMemorySize, LDSB);

    // sentinel-fill the ring, zero the flags, then bf16(H0) -> slot 0
    hipMemsetAsync(comm, 0x7F, (size_t)RING * SLOT * 2, stream);
    hipMemsetAsync(flags2, 0, NFLAGS * sizeof(int), stream);
    hipLaunchKernelGGL(rnn_init_kernel, dim3(64), dim3(256), 0, stream, H0, comm);
    hipLaunchKernelGGL(rnn_seq_kernel, dim3(NGRP * NSL), dim3(THREADS), LDSB, stream,
                       X, Wih, Whh, bh, out, comm, flags2);
}